// Round 9
// baseline (369.226 us; speedup 1.0000x reference)
//
#include <hip/hip_runtime.h>
#include <math.h>

#define N_NODES 50000
#define N_EDGES 800000
#define BUCKET 64
#define SCAT_BLKS 392   // 8 dst-range groups x 49 chunk groups
#define QPG 4082        // int4-quads per chunk group (49*4082 >= 200000)
#define GEMM_BLKS 196   // ceil(3125 row-tiles / 16)
// F_IN = HID = 128, C = 40

typedef __attribute__((ext_vector_type(8))) short short8;
typedef __attribute__((ext_vector_type(4))) float f32x4;

__device__ __forceinline__ ushort f2bf(float f) {
    union { float f; uint u; } v; v.f = f;
    uint r = v.u + 0x7FFFu + ((v.u >> 16) & 1u);  // RNE
    return (ushort)(r >> 16);
}
__device__ __forceinline__ float bflo(uint p) {
    union { uint u; float f; } v; v.u = p << 16; return v.f;
}
__device__ __forceinline__ float bfhi(uint p) {
    union { uint u; float f; } v; v.u = p & 0xFFFF0000u; return v.f;
}

// ---------------- fused: range-partitioned scatter + gemm1 (MFMA, fp32->bf16 inline) ----------------
__global__ __launch_bounds__(512) void fused_gemm1_scatter_k(
        const float* __restrict__ Af, const float* __restrict__ W, ushort* __restrict__ Y,
        const int* __restrict__ src, const int* __restrict__ dst,
        int* __restrict__ cnt, ushort* __restrict__ colb) {
    constexpr int NT = 8;
    __shared__ ushort sB[4 * NT * 64 * 8];
    const int tid = threadIdx.x;

    if (blockIdx.x < SCAT_BLKS) {
        const int r = blockIdx.x & 7;
        const int g = blockIdx.x >> 3;
        const int lo = r * 6250;
        const int4* s32 = reinterpret_cast<const int4*>(src);
        const int4* d32 = reinterpret_cast<const int4*>(dst);
        const int qbeg = g * QPG + tid;
        const int qend = min((g + 1) * QPG, N_EDGES / 4);
#pragma unroll
        for (int u = 0; u < 8; u++) {
            const int q = qbeg + u * 512;
            if (q < qend) {
                const int4 d4 = d32[q];
                const int4 s4 = s32[q];
                if ((uint)(d4.x - lo) < 6250u) {
                    int p = atomicAdd(&cnt[d4.x], 1);
                    colb[(size_t)d4.x * BUCKET + p] = (ushort)s4.x;
                }
                if ((uint)(d4.y - lo) < 6250u) {
                    int p = atomicAdd(&cnt[d4.y], 1);
                    colb[(size_t)d4.y * BUCKET + p] = (ushort)s4.y;
                }
                if ((uint)(d4.z - lo) < 6250u) {
                    int p = atomicAdd(&cnt[d4.z], 1);
                    colb[(size_t)d4.z * BUCKET + p] = (ushort)s4.z;
                }
                if ((uint)(d4.w - lo) < 6250u) {
                    int p = atomicAdd(&cnt[d4.w], 1);
                    colb[(size_t)d4.w * BUCKET + p] = (ushort)s4.w;
                }
            }
        }
        return;
    }

    // ---- gemm role: Y = cvt(x) @ W1, raw (no dinv scaling; scatter concurrent) ----
    constexpr int FP = NT * 16;
    for (int i = tid; i < 128 * FP; i += 512) {
        const int k = i / FP, n = i % FP;
        const int s = k >> 5, r2 = (k >> 3) & 3, j = k & 7;
        const int t = n >> 4, nl = n & 15;
        const int l = r2 * 16 + nl;
        const int lp = (l & 56) | ((l + (l >> 3)) & 7);
        sB[(((s * NT + t) * 64) + lp) * 8 + j] = f2bf(W[k * 128 + n]);
    }
    __syncthreads();

    const int wid = tid >> 6, lane = tid & 63;
    const int lp = (lane & 56) | ((lane + (lane >> 3)) & 7);
    const int t0 = (blockIdx.x - SCAT_BLKS) * 16 + wid * 2;
    const int t1 = t0 + 1;
    const int t0c = min(t0, N_NODES / 16 - 1);
    const int t1c = min(t1, N_NODES / 16 - 1);

    f32x4 acc[2][NT];
#pragma unroll
    for (int u = 0; u < 2; u++)
#pragma unroll
        for (int t = 0; t < NT; t++) acc[u][t] = (f32x4){0.f, 0.f, 0.f, 0.f};

#pragma unroll
    for (int s = 0; s < 4; s++) {
        short8 a0, a1;
        const int ko = 32 * s + 8 * (lane >> 4);
        const float4* p0 = reinterpret_cast<const float4*>(Af + (size_t)(t0c * 16 + (lane & 15)) * 128 + ko);
        const float4* p1 = reinterpret_cast<const float4*>(Af + (size_t)(t1c * 16 + (lane & 15)) * 128 + ko);
        float4 u0 = p0[0], u1 = p0[1], v0 = p1[0], v1 = p1[1];
        a0[0] = f2bf(u0.x); a0[1] = f2bf(u0.y); a0[2] = f2bf(u0.z); a0[3] = f2bf(u0.w);
        a0[4] = f2bf(u1.x); a0[5] = f2bf(u1.y); a0[6] = f2bf(u1.z); a0[7] = f2bf(u1.w);
        a1[0] = f2bf(v0.x); a1[1] = f2bf(v0.y); a1[2] = f2bf(v0.z); a1[3] = f2bf(v0.w);
        a1[4] = f2bf(v1.x); a1[5] = f2bf(v1.y); a1[6] = f2bf(v1.z); a1[7] = f2bf(v1.w);
#pragma unroll
        for (int t = 0; t < NT; t++) {
            short8 b = *reinterpret_cast<const short8*>(&sB[(((s * NT + t) * 64) + lp) * 8]);
            acc[0][t] = __builtin_amdgcn_mfma_f32_16x16x32_bf16(a0, b, acc[0][t], 0, 0, 0);
            acc[1][t] = __builtin_amdgcn_mfma_f32_16x16x32_bf16(a1, b, acc[1][t], 0, 0, 0);
        }
    }

    const int rl = 4 * (lane >> 4), cl = lane & 15;
#pragma unroll
    for (int u = 0; u < 2; u++) {
        const int tile = u ? t1 : t0;
        if (tile >= N_NODES / 16) continue;
        const int row0 = tile * 16;
#pragma unroll
        for (int t = 0; t < NT; t++) {
            const int c = 16 * t + cl;
#pragma unroll
            for (int g = 0; g < 4; g++)
                Y[(size_t)(row0 + rl + g) * 128 + c] = f2bf(acc[u][t][g]);
        }
    }
}

// ---------------- scale rows of a bf16 [N x 128] buffer by rsqrt(cnt+1) (in-place) ----------------
__global__ __launch_bounds__(256) void scale_rows_k(ushort* __restrict__ B,
                                                    const int* __restrict__ cnt) {
    const int idx = blockIdx.x * 256 + threadIdx.x;  // one uint4 (8 bf16) per thread
    if (idx >= N_NODES * 16) return;
    const float di = rsqrtf((float)(cnt[idx >> 4] + 1));
    uint4 v = reinterpret_cast<uint4*>(B)[idx];
    uint4 o;
    o.x = (uint)f2bf(bflo(v.x) * di) | ((uint)f2bf(bfhi(v.x) * di) << 16);
    o.y = (uint)f2bf(bflo(v.y) * di) | ((uint)f2bf(bfhi(v.y) * di) << 16);
    o.z = (uint)f2bf(bflo(v.z) * di) | ((uint)f2bf(bfhi(v.z) * di) << 16);
    o.w = (uint)f2bf(bflo(v.w) * di) | ((uint)f2bf(bfhi(v.w) * di) << 16);
    reinterpret_cast<uint4*>(B)[idx] = o;
}

// ---------------- MFMA GEMM (layers 2,3) with dinv-scaled epilogue ----------------
template <int NT>
__global__ __launch_bounds__(512) void gemm_scaled_k(const ushort* __restrict__ Ab,
                                                     const float* __restrict__ W,
                                                     const int* __restrict__ cnt,
                                                     ushort* __restrict__ Y,
                                                     const int fout) {
    __shared__ ushort sB[4 * NT * 64 * 8];
    const int tid = threadIdx.x;
    constexpr int FP = NT * 16;
    for (int i = tid; i < 128 * FP; i += 512) {
        const int k = i / FP, n = i % FP;
        const int s = k >> 5, r2 = (k >> 3) & 3, j = k & 7;
        const int t = n >> 4, nl = n & 15;
        const int l = r2 * 16 + nl;
        const int lp = (l & 56) | ((l + (l >> 3)) & 7);
        sB[(((s * NT + t) * 64) + lp) * 8 + j] = (n < fout) ? f2bf(W[k * fout + n]) : (ushort)0;
    }
    __syncthreads();

    const int wid = tid >> 6, lane = tid & 63;
    const int lp = (lane & 56) | ((lane + (lane >> 3)) & 7);
    const int t0 = blockIdx.x * 16 + wid * 2;
    const int t1 = t0 + 1;
    const int t0c = min(t0, N_NODES / 16 - 1);
    const int t1c = min(t1, N_NODES / 16 - 1);

    f32x4 acc[2][NT];
#pragma unroll
    for (int u = 0; u < 2; u++)
#pragma unroll
        for (int t = 0; t < NT; t++) acc[u][t] = (f32x4){0.f, 0.f, 0.f, 0.f};

#pragma unroll
    for (int s = 0; s < 4; s++) {
        const int ko = 32 * s + 8 * (lane >> 4);
        short8 a0 = *reinterpret_cast<const short8*>(Ab + (size_t)(t0c * 16 + (lane & 15)) * 128 + ko);
        short8 a1 = *reinterpret_cast<const short8*>(Ab + (size_t)(t1c * 16 + (lane & 15)) * 128 + ko);
#pragma unroll
        for (int t = 0; t < NT; t++) {
            short8 b = *reinterpret_cast<const short8*>(&sB[(((s * NT + t) * 64) + lp) * 8]);
            acc[0][t] = __builtin_amdgcn_mfma_f32_16x16x32_bf16(a0, b, acc[0][t], 0, 0, 0);
            acc[1][t] = __builtin_amdgcn_mfma_f32_16x16x32_bf16(a1, b, acc[1][t], 0, 0, 0);
        }
    }

    const int rl = 4 * (lane >> 4), cl = lane & 15;
#pragma unroll
    for (int u = 0; u < 2; u++) {
        const int tile = u ? t1 : t0;
        if (tile >= N_NODES / 16) continue;
        const int row0 = tile * 16;
#pragma unroll
        for (int g = 0; g < 4; g++) {
            const int row = row0 + rl + g;
            const float dr = rsqrtf((float)(cnt[row] + 1));
#pragma unroll
            for (int t = 0; t < NT; t++) {
                const int c = 16 * t + cl;
                if (NT == 3 && c >= fout) continue;
                Y[(size_t)row * fout + c] = f2bf(acc[u][t][g] * dr);
            }
        }
    }
}

// ---------------- feature-pass gather (pure add, F=128): wave = node, 4 passes of 32 feats ----------------
// Pass p (blockIdx.y) reads only 64B/row -> 3.2MB working set fits per-XCD L2.
// 4 lane-groups of 16 process 4 edges concurrently; __shfl_xor butterfly combines.
// out[i][fp] = relu( di * ( sum_j XWn[j][fp] + XWn[i][fp] ) + b[fp] )
__global__ __launch_bounds__(256) void gather_fp_k(const ushort* __restrict__ XWn,
                                                   const int* __restrict__ cnt,
                                                   const ushort* __restrict__ colb,
                                                   const float* __restrict__ bias,
                                                   ushort* __restrict__ out) {
    const int wid = threadIdx.x >> 6, lane = threadIdx.x & 63;
    const int node = blockIdx.x * 4 + wid;
    const int p = blockIdx.y;                 // feature pass 0..3
    if (node >= N_NODES) return;
    const int n = cnt[node];
    const float di = rsqrtf((float)(n + 1));
    const int g = lane >> 4;                  // edge group 0..3
    const int fl = lane & 15;                 // feature lane within pass
    const int fo = p * 16 + fl;               // uint offset in row (stride 64)
    const uint* XW32 = reinterpret_cast<const uint*>(XWn);
    const ushort* bkt = colb + (size_t)node * BUCKET;

    float a0 = 0.f, a1 = 0.f, b0 = 0.f, b1 = 0.f;
    float c0 = 0.f, c1 = 0.f, d0 = 0.f, d1 = 0.f;
    int e = g;
    for (; e + 12 < n; e += 16) {             // 4 row-loads in flight per group
        const int s0 = bkt[e], s1 = bkt[e + 4], s2 = bkt[e + 8], s3 = bkt[e + 12];
        const uint p0 = XW32[(size_t)s0 * 64 + fo];
        const uint p1 = XW32[(size_t)s1 * 64 + fo];
        const uint p2 = XW32[(size_t)s2 * 64 + fo];
        const uint p3 = XW32[(size_t)s3 * 64 + fo];
        a0 += bflo(p0); a1 += bfhi(p0);
        b0 += bflo(p1); b1 += bfhi(p1);
        c0 += bflo(p2); c1 += bfhi(p2);
        d0 += bflo(p3); d1 += bfhi(p3);
    }
    for (; e < n; e += 4) {
        const int s0 = bkt[e];
        const uint p0 = XW32[(size_t)s0 * 64 + fo];
        a0 += bflo(p0); a1 += bfhi(p0);
    }
    a0 = (a0 + b0) + (c0 + d0);
    a1 = (a1 + b1) + (c1 + d1);
    a0 += __shfl_xor(a0, 16); a0 += __shfl_xor(a0, 32);
    a1 += __shfl_xor(a1, 16); a1 += __shfl_xor(a1, 32);
    if (g == 0) {
        const uint ps = XW32[(size_t)node * 64 + fo];
        const float o0 = fmaxf(fmaf(di, a0 + bflo(ps), bias[32 * p + 2 * fl]), 0.f);
        const float o1 = fmaxf(fmaf(di, a1 + bfhi(ps), bias[32 * p + 2 * fl + 1]), 0.f);
        reinterpret_cast<uint*>(out)[(size_t)node * 64 + fo] =
            (uint)f2bf(o0) | ((uint)f2bf(o1) << 16);
    }
}

// ---------------- layer 3: pure-add gather (F=40, pre-scaled) + log-softmax ----------------
__global__ __launch_bounds__(256) void gather40_lsm_k(const ushort* __restrict__ XWn,
                                                      const int* __restrict__ cnt,
                                                      const ushort* __restrict__ colb,
                                                      const float* __restrict__ bias,
                                                      float* __restrict__ out) {
    const int node = (blockIdx.x * 256 + threadIdx.x) >> 6;
    const int lane = threadIdx.x & 63;
    if (node >= N_NODES) return;
    const int g = lane < 20 ? 0 : (lane < 40 ? 1 : 2);
    const int ll = lane - g * 20;
    const int llc = min(ll, 19);
    const int n = cnt[node];
    const float di = rsqrtf((float)(n + 1));
    const uint* XW32 = reinterpret_cast<const uint*>(XWn);  // row stride 20 uints

    float a0 = 0.f, a1 = 0.f;
    for (int e = g; e < n; e += 3) {
        const ushort s = colb[(size_t)node * BUCKET + e];
        const uint p = XW32[(size_t)s * 20 + llc];
        a0 += bflo(p); a1 += bfhi(p);
    }
    const float t1 = __shfl(a0, lane + 20), t2 = __shfl(a0, lane + 40);
    const float u1 = __shfl(a1, lane + 20), u2 = __shfl(a1, lane + 40);
    float v0 = -INFINITY, v1 = -INFINITY;
    if (lane < 20) {
        const uint ps = XW32[(size_t)node * 20 + lane];
        v0 = fmaf(di, (a0 + t1 + t2) + bflo(ps), bias[2 * lane]);
        v1 = fmaf(di, (a1 + u1 + u2) + bfhi(ps), bias[2 * lane + 1]);
    }
    float m = fmaxf(v0, v1);
#pragma unroll
    for (int o = 32; o > 0; o >>= 1) m = fmaxf(m, __shfl_xor(m, o));
    float s = (lane < 20) ? (expf(v0 - m) + expf(v1 - m)) : 0.f;
#pragma unroll
    for (int o = 32; o > 0; o >>= 1) s += __shfl_xor(s, o);
    if (lane < 20) {
        const float ls = m + logf(s);
        float2 r; r.x = v0 - ls; r.y = v1 - ls;
        reinterpret_cast<float2*>(out)[(size_t)node * 20 + lane] = r;
    }
}

extern "C" void kernel_launch(void* const* d_in, const int* in_sizes, int n_in,
                              void* d_out, int out_size, void* d_ws, size_t ws_size,
                              hipStream_t stream) {
    const float* x  = (const float*)d_in[0];
    const float* W1 = (const float*)d_in[1];
    const float* b1 = (const float*)d_in[2];
    const float* W2 = (const float*)d_in[3];
    const float* b2 = (const float*)d_in[4];
    const float* W3 = (const float*)d_in[5];
    const float* b3 = (const float*)d_in[6];
    const int* ei   = (const int*)d_in[7];
    const int* srcp = ei;
    const int* dstp = ei + N_EDGES;
    float* out = (float*)d_out;

    // workspace: cnt[50176 int] colb[50000*64 ushort] B0[N*128 bf16] B1[N*128 bf16]
    int*    cnt  = (int*)d_ws;
    ushort* colb = (ushort*)(cnt + 50176);
    ushort* B0   = colb + (size_t)N_NODES * BUCKET;   // 16B aligned
    ushort* B1   = B0 + (size_t)N_NODES * 128;

    const int NB_W = (N_NODES * 64) / 256;   // 12500 (one wave per node)

    hipMemsetAsync(cnt, 0, 50176 * sizeof(int), stream);
    // range-partitioned scatter (XCD-local bucket lines) overlapped with gemm1 (raw XW1)
    fused_gemm1_scatter_k<<<SCAT_BLKS + GEMM_BLKS, 512, 0, stream>>>(
        x, W1, B1, srcp, dstp, cnt, colb);
    // XW1n = XW1 * dinv[row]  (makes layer-1 gather a pure add)
    scale_rows_k<<<3125, 256, 0, stream>>>(B1, cnt);
    // h1 = relu(di*(sum XW1n + self) + b1)  — 4 feature passes, L2-resident working set
    gather_fp_k<<<dim3(12500, 4), 256, 0, stream>>>(B1, cnt, colb, b1, B0);
    // XW2n = (h1 @ W2) * dinv[row]
    gemm_scaled_k<8><<<GEMM_BLKS, 512, 0, stream>>>(B0, W2, cnt, B1, 128);
    // h2 = relu(di*(sum XW2n + self) + b2)
    gather_fp_k<<<dim3(12500, 4), 256, 0, stream>>>(B1, cnt, colb, b2, B0);
    // XW3n = (h2 @ W3) * dinv[row]
    gemm_scaled_k<3><<<GEMM_BLKS, 512, 0, stream>>>(B0, W3, cnt, B1, 40);
    // logits + log-softmax
    gather40_lsm_k<<<NB_W, 256, 0, stream>>>(B1, cnt, colb, b3, out);
}

// Round 10
// 264.046 us; speedup vs baseline: 1.3983x; 1.3983x over previous
//
#include <hip/hip_runtime.h>
#include <math.h>

#define N_NODES 50000
#define N_EDGES 800000
#define BUCKET 64
#define SCAT_BLKS 392   // 8 dst-range groups x 49 chunk groups
#define QPG 4082        // int4-quads per chunk group (49*4082 >= 200000)
#define GEMM_BLKS 196   // ceil(3125 row-tiles / 16)
// F_IN = HID = 128, C = 40

typedef __attribute__((ext_vector_type(8))) short short8;
typedef __attribute__((ext_vector_type(4))) float f32x4;

__device__ __forceinline__ ushort f2bf(float f) {
    union { float f; uint u; } v; v.f = f;
    uint r = v.u + 0x7FFFu + ((v.u >> 16) & 1u);  // RNE
    return (ushort)(r >> 16);
}
__device__ __forceinline__ float bflo(uint p) {
    union { uint u; float f; } v; v.u = p << 16; return v.f;
}
__device__ __forceinline__ float bfhi(uint p) {
    union { uint u; float f; } v; v.u = p & 0xFFFF0000u; return v.f;
}

// ---------------- fused: range-partitioned scatter + gemm1 (MFMA, fp32->bf16 inline) ----------------
__global__ __launch_bounds__(512) void fused_gemm1_scatter_k(
        const float* __restrict__ Af, const float* __restrict__ W, ushort* __restrict__ Y,
        const int* __restrict__ src, const int* __restrict__ dst,
        int* __restrict__ cnt, ushort* __restrict__ colb) {
    constexpr int NT = 8;
    __shared__ ushort sB[4 * NT * 64 * 8];
    const int tid = threadIdx.x;

    if (blockIdx.x < SCAT_BLKS) {
        const int r = blockIdx.x & 7;
        const int g = blockIdx.x >> 3;
        const int lo = r * 6250;
        const int4* s32 = reinterpret_cast<const int4*>(src);
        const int4* d32 = reinterpret_cast<const int4*>(dst);
        const int qbeg = g * QPG + tid;
        const int qend = min((g + 1) * QPG, N_EDGES / 4);
#pragma unroll
        for (int u = 0; u < 8; u++) {
            const int q = qbeg + u * 512;
            if (q < qend) {
                const int4 d4 = d32[q];
                const int4 s4 = s32[q];
                if ((uint)(d4.x - lo) < 6250u) {
                    int p = atomicAdd(&cnt[d4.x], 1);
                    colb[(size_t)d4.x * BUCKET + p] = (ushort)s4.x;
                }
                if ((uint)(d4.y - lo) < 6250u) {
                    int p = atomicAdd(&cnt[d4.y], 1);
                    colb[(size_t)d4.y * BUCKET + p] = (ushort)s4.y;
                }
                if ((uint)(d4.z - lo) < 6250u) {
                    int p = atomicAdd(&cnt[d4.z], 1);
                    colb[(size_t)d4.z * BUCKET + p] = (ushort)s4.z;
                }
                if ((uint)(d4.w - lo) < 6250u) {
                    int p = atomicAdd(&cnt[d4.w], 1);
                    colb[(size_t)d4.w * BUCKET + p] = (ushort)s4.w;
                }
            }
        }
        return;
    }

    // ---- gemm role: Y = cvt(x) @ W1, raw ----
    constexpr int FP = NT * 16;
    for (int i = tid; i < 128 * FP; i += 512) {
        const int k = i / FP, n = i % FP;
        const int s = k >> 5, r2 = (k >> 3) & 3, j = k & 7;
        const int t = n >> 4, nl = n & 15;
        const int l = r2 * 16 + nl;
        const int lp = (l & 56) | ((l + (l >> 3)) & 7);
        sB[(((s * NT + t) * 64) + lp) * 8 + j] = f2bf(W[k * 128 + n]);
    }
    __syncthreads();

    const int wid = tid >> 6, lane = tid & 63;
    const int lp = (lane & 56) | ((lane + (lane >> 3)) & 7);
    const int t0 = (blockIdx.x - SCAT_BLKS) * 16 + wid * 2;
    const int t1 = t0 + 1;
    const int t0c = min(t0, N_NODES / 16 - 1);
    const int t1c = min(t1, N_NODES / 16 - 1);

    f32x4 acc[2][NT];
#pragma unroll
    for (int u = 0; u < 2; u++)
#pragma unroll
        for (int t = 0; t < NT; t++) acc[u][t] = (f32x4){0.f, 0.f, 0.f, 0.f};

#pragma unroll
    for (int s = 0; s < 4; s++) {
        short8 a0, a1;
        const int ko = 32 * s + 8 * (lane >> 4);
        const float4* p0 = reinterpret_cast<const float4*>(Af + (size_t)(t0c * 16 + (lane & 15)) * 128 + ko);
        const float4* p1 = reinterpret_cast<const float4*>(Af + (size_t)(t1c * 16 + (lane & 15)) * 128 + ko);
        float4 u0 = p0[0], u1 = p0[1], v0 = p1[0], v1 = p1[1];
        a0[0] = f2bf(u0.x); a0[1] = f2bf(u0.y); a0[2] = f2bf(u0.z); a0[3] = f2bf(u0.w);
        a0[4] = f2bf(u1.x); a0[5] = f2bf(u1.y); a0[6] = f2bf(u1.z); a0[7] = f2bf(u1.w);
        a1[0] = f2bf(v0.x); a1[1] = f2bf(v0.y); a1[2] = f2bf(v0.z); a1[3] = f2bf(v0.w);
        a1[4] = f2bf(v1.x); a1[5] = f2bf(v1.y); a1[6] = f2bf(v1.z); a1[7] = f2bf(v1.w);
#pragma unroll
        for (int t = 0; t < NT; t++) {
            short8 b = *reinterpret_cast<const short8*>(&sB[(((s * NT + t) * 64) + lp) * 8]);
            acc[0][t] = __builtin_amdgcn_mfma_f32_16x16x32_bf16(a0, b, acc[0][t], 0, 0, 0);
            acc[1][t] = __builtin_amdgcn_mfma_f32_16x16x32_bf16(a1, b, acc[1][t], 0, 0, 0);
        }
    }

    const int rl = 4 * (lane >> 4), cl = lane & 15;
#pragma unroll
    for (int u = 0; u < 2; u++) {
        const int tile = u ? t1 : t0;
        if (tile >= N_NODES / 16) continue;
        const int row0 = tile * 16;
#pragma unroll
        for (int t = 0; t < NT; t++) {
            const int c = 16 * t + cl;
#pragma unroll
            for (int g = 0; g < 4; g++)
                Y[(size_t)(row0 + rl + g) * 128 + c] = f2bf(acc[u][t][g]);
        }
    }
}

// ---------------- MFMA GEMM (layers 2,3) with dinv-scaled epilogue ----------------
template <int NT>
__global__ __launch_bounds__(512) void gemm_scaled_k(const ushort* __restrict__ Ab,
                                                     const float* __restrict__ W,
                                                     const int* __restrict__ cnt,
                                                     ushort* __restrict__ Y,
                                                     const int fout) {
    __shared__ ushort sB[4 * NT * 64 * 8];
    const int tid = threadIdx.x;
    constexpr int FP = NT * 16;
    for (int i = tid; i < 128 * FP; i += 512) {
        const int k = i / FP, n = i % FP;
        const int s = k >> 5, r2 = (k >> 3) & 3, j = k & 7;
        const int t = n >> 4, nl = n & 15;
        const int l = r2 * 16 + nl;
        const int lp = (l & 56) | ((l + (l >> 3)) & 7);
        sB[(((s * NT + t) * 64) + lp) * 8 + j] = (n < fout) ? f2bf(W[k * fout + n]) : (ushort)0;
    }
    __syncthreads();

    const int wid = tid >> 6, lane = tid & 63;
    const int lp = (lane & 56) | ((lane + (lane >> 3)) & 7);
    const int t0 = blockIdx.x * 16 + wid * 2;
    const int t1 = t0 + 1;
    const int t0c = min(t0, N_NODES / 16 - 1);
    const int t1c = min(t1, N_NODES / 16 - 1);

    f32x4 acc[2][NT];
#pragma unroll
    for (int u = 0; u < 2; u++)
#pragma unroll
        for (int t = 0; t < NT; t++) acc[u][t] = (f32x4){0.f, 0.f, 0.f, 0.f};

#pragma unroll
    for (int s = 0; s < 4; s++) {
        const int ko = 32 * s + 8 * (lane >> 4);
        short8 a0 = *reinterpret_cast<const short8*>(Ab + (size_t)(t0c * 16 + (lane & 15)) * 128 + ko);
        short8 a1 = *reinterpret_cast<const short8*>(Ab + (size_t)(t1c * 16 + (lane & 15)) * 128 + ko);
#pragma unroll
        for (int t = 0; t < NT; t++) {
            short8 b = *reinterpret_cast<const short8*>(&sB[(((s * NT + t) * 64) + lp) * 8]);
            acc[0][t] = __builtin_amdgcn_mfma_f32_16x16x32_bf16(a0, b, acc[0][t], 0, 0, 0);
            acc[1][t] = __builtin_amdgcn_mfma_f32_16x16x32_bf16(a1, b, acc[1][t], 0, 0, 0);
        }
    }

    const int rl = 4 * (lane >> 4), cl = lane & 15;
#pragma unroll
    for (int u = 0; u < 2; u++) {
        const int tile = u ? t1 : t0;
        if (tile >= N_NODES / 16) continue;
        const int row0 = tile * 16;
#pragma unroll
        for (int g = 0; g < 4; g++) {
            const int row = row0 + rl + g;
            const float dr = rsqrtf((float)(cnt[row] + 1));
#pragma unroll
            for (int t = 0; t < NT; t++) {
                const int c = 16 * t + cl;
                if (NT == 3 && c >= fout) continue;
                Y[(size_t)row * fout + c] = f2bf(acc[u][t][g] * dr);
            }
        }
    }
}

// ---------------- half-row two-pass gather (F=128): wave = node, 2 edges per load ----------------
// Pass p (blockIdx.x >= 12500) covers features [p*64, p*64+64) = 128B/row -> 6.4MB line
// working set per pass (fits per-XCD L2). Lanes 0-31 = edge e, lanes 32-63 = edge e+1 -> one
// full-width load instruction per 2 edges (same issue count as full-row, half the traffic/pass).
// WEIGHTED (layer 1): per-edge w_j = rsqrt(cnt[src]+1) preloaded lane-parallel, shfl-broadcast.
// pure (layer 2): input rows pre-scaled by gemm epilogue.
template <bool WEIGHTED>
__global__ __launch_bounds__(256) void gather_half_k(const ushort* __restrict__ XW,
                                                     const int* __restrict__ cnt,
                                                     const ushort* __restrict__ colb,
                                                     const float* __restrict__ bias,
                                                     ushort* __restrict__ out) {
    const int pass = (blockIdx.x >= 12500) ? 1 : 0;
    const int nb = blockIdx.x - pass * 12500;
    const int wid = threadIdx.x >> 6, lane = threadIdx.x & 63;
    const int node = nb * 4 + wid;                 // 12500*4 = 50000 exactly
    const int half = lane >> 5, fl = lane & 31;
    const int fo = pass * 32 + fl;                 // uint offset in row (stride 64)
    const int n = cnt[node];
    const float di = rsqrtf((float)(n + 1));

    // lane-parallel preload of bucket (+weights)
    int sl = 0; float wl = 0.f;
    if (lane < n) {
        sl = colb[(size_t)node * BUCKET + lane];
        if (WEIGHTED) wl = rsqrtf((float)(cnt[sl] + 1));
    }
    const uint* XW32 = reinterpret_cast<const uint*>(XW);

    float a0 = 0.f, a1 = 0.f, b0 = 0.f, b1 = 0.f;
    float c0 = 0.f, c1 = 0.f, d0 = 0.f, d1 = 0.f;
    for (int e0 = 0; e0 < n; e0 += 8) {
        const int e_0 = e0 + half,     e_1 = e0 + 2 + half;
        const int e_2 = e0 + 4 + half, e_3 = e0 + 6 + half;
        const int s0 = __shfl(sl, e_0 & 63), s1 = __shfl(sl, e_1 & 63);
        const int s2 = __shfl(sl, e_2 & 63), s3 = __shfl(sl, e_3 & 63);
        uint p0 = XW32[(size_t)s0 * 64 + fo];
        uint p1 = XW32[(size_t)s1 * 64 + fo];
        uint p2 = XW32[(size_t)s2 * 64 + fo];
        uint p3 = XW32[(size_t)s3 * 64 + fo];
        if (WEIGHTED) {
            float w0 = __shfl(wl, e_0 & 63), w1 = __shfl(wl, e_1 & 63);
            float w2 = __shfl(wl, e_2 & 63), w3 = __shfl(wl, e_3 & 63);
            w0 = (e_0 < n) ? w0 : 0.f; w1 = (e_1 < n) ? w1 : 0.f;
            w2 = (e_2 < n) ? w2 : 0.f; w3 = (e_3 < n) ? w3 : 0.f;
            a0 = fmaf(bflo(p0), w0, a0); a1 = fmaf(bfhi(p0), w0, a1);
            b0 = fmaf(bflo(p1), w1, b0); b1 = fmaf(bfhi(p1), w1, b1);
            c0 = fmaf(bflo(p2), w2, c0); c1 = fmaf(bfhi(p2), w2, c1);
            d0 = fmaf(bflo(p3), w3, d0); d1 = fmaf(bfhi(p3), w3, d1);
        } else {
            p0 = (e_0 < n) ? p0 : 0u; p1 = (e_1 < n) ? p1 : 0u;
            p2 = (e_2 < n) ? p2 : 0u; p3 = (e_3 < n) ? p3 : 0u;
            a0 += bflo(p0); a1 += bfhi(p0);
            b0 += bflo(p1); b1 += bfhi(p1);
            c0 += bflo(p2); c1 += bfhi(p2);
            d0 += bflo(p3); d1 += bfhi(p3);
        }
    }
    float t0 = (a0 + b0) + (c0 + d0);
    float t1 = (a1 + b1) + (c1 + d1);
    t0 += __shfl_xor(t0, 32);   // combine the two edge-halves (same fo in both)
    t1 += __shfl_xor(t1, 32);
    if (half == 0) {
        const uint ps = XW32[(size_t)node * 64 + fo];
        float s0, s1;
        if (WEIGHTED) {  // out = relu(di*(agg + di*self) + b)
            s0 = fmaf(di, bflo(ps), t0);
            s1 = fmaf(di, bfhi(ps), t1);
        } else {         // rows pre-scaled: out = relu(di*(agg + self_n) + b)
            s0 = t0 + bflo(ps);
            s1 = t1 + bfhi(ps);
        }
        const float o0 = fmaxf(fmaf(di, s0, bias[2 * fo]), 0.f);
        const float o1 = fmaxf(fmaf(di, s1, bias[2 * fo + 1]), 0.f);
        reinterpret_cast<uint*>(out)[(size_t)node * 64 + fo] =
            (uint)f2bf(o0) | ((uint)f2bf(o1) << 16);
    }
}

// ---------------- layer 3: pure-add gather (F=40, pre-scaled) + log-softmax, 2x unroll ----------------
__global__ __launch_bounds__(256) void gather40_lsm_k(const ushort* __restrict__ XWn,
                                                      const int* __restrict__ cnt,
                                                      const ushort* __restrict__ colb,
                                                      const float* __restrict__ bias,
                                                      float* __restrict__ out) {
    const int node = (blockIdx.x * 256 + threadIdx.x) >> 6;
    const int lane = threadIdx.x & 63;
    if (node >= N_NODES) return;
    const int g = lane < 20 ? 0 : (lane < 40 ? 1 : 2);
    const int ll = lane - g * 20;
    const int llc = min(ll, 19);
    const int n = cnt[node];
    const float di = rsqrtf((float)(n + 1));
    const uint* XW32 = reinterpret_cast<const uint*>(XWn);  // row stride 20 uints
    const ushort* bkt = colb + (size_t)node * BUCKET;

    float a0 = 0.f, a1 = 0.f, b0 = 0.f, b1 = 0.f;
    int e = g;
    for (; e + 3 < n; e += 6) {                     // 6 edges in flight per wave
        const ushort s0 = bkt[e], s1 = bkt[e + 3];
        const uint p0 = XW32[(size_t)s0 * 20 + llc];
        const uint p1 = XW32[(size_t)s1 * 20 + llc];
        a0 += bflo(p0); a1 += bfhi(p0);
        b0 += bflo(p1); b1 += bfhi(p1);
    }
    for (; e < n; e += 3) {
        const ushort s = bkt[e];
        const uint p = XW32[(size_t)s * 20 + llc];
        a0 += bflo(p); a1 += bfhi(p);
    }
    a0 += b0; a1 += b1;
    const float t1 = __shfl(a0, lane + 20), t2 = __shfl(a0, lane + 40);
    const float u1 = __shfl(a1, lane + 20), u2 = __shfl(a1, lane + 40);
    float v0 = -INFINITY, v1 = -INFINITY;
    if (lane < 20) {
        const uint ps = XW32[(size_t)node * 20 + lane];
        v0 = fmaf(di, (a0 + t1 + t2) + bflo(ps), bias[2 * lane]);
        v1 = fmaf(di, (a1 + u1 + u2) + bfhi(ps), bias[2 * lane + 1]);
    }
    float m = fmaxf(v0, v1);
#pragma unroll
    for (int o = 32; o > 0; o >>= 1) m = fmaxf(m, __shfl_xor(m, o));
    float s = (lane < 20) ? (expf(v0 - m) + expf(v1 - m)) : 0.f;
#pragma unroll
    for (int o = 32; o > 0; o >>= 1) s += __shfl_xor(s, o);
    if (lane < 20) {
        const float ls = m + logf(s);
        float2 r; r.x = v0 - ls; r.y = v1 - ls;
        reinterpret_cast<float2*>(out)[(size_t)node * 20 + lane] = r;
    }
}

extern "C" void kernel_launch(void* const* d_in, const int* in_sizes, int n_in,
                              void* d_out, int out_size, void* d_ws, size_t ws_size,
                              hipStream_t stream) {
    const float* x  = (const float*)d_in[0];
    const float* W1 = (const float*)d_in[1];
    const float* b1 = (const float*)d_in[2];
    const float* W2 = (const float*)d_in[3];
    const float* b2 = (const float*)d_in[4];
    const float* W3 = (const float*)d_in[5];
    const float* b3 = (const float*)d_in[6];
    const int* ei   = (const int*)d_in[7];
    const int* srcp = ei;
    const int* dstp = ei + N_EDGES;
    float* out = (float*)d_out;

    // workspace: cnt[50176 int] colb[50000*64 ushort] B0[N*128 bf16] B1[N*128 bf16]
    int*    cnt  = (int*)d_ws;
    ushort* colb = (ushort*)(cnt + 50176);
    ushort* B0   = colb + (size_t)N_NODES * BUCKET;   // 16B aligned
    ushort* B1   = B0 + (size_t)N_NODES * 128;

    const int NB_W = (N_NODES * 64) / 256;   // 12500 (one wave per node)

    hipMemsetAsync(cnt, 0, 50176 * sizeof(int), stream);
    // range-partitioned scatter overlapped with gemm1 (XW1 = cvt(x) @ W1, raw)
    fused_gemm1_scatter_k<<<SCAT_BLKS + GEMM_BLKS, 512, 0, stream>>>(
        x, W1, B1, srcp, dstp, cnt, colb);
    // h1 = relu(Ahat @ XW1 + b1) — weighted, two sequential half-row passes
    gather_half_k<true><<<25000, 256, 0, stream>>>(B1, cnt, colb, b1, B0);
    // XW2n = (h1 @ W2) * dinv[row]
    gemm_scaled_k<8><<<GEMM_BLKS, 512, 0, stream>>>(B0, W2, cnt, B1, 128);
    // h2 = relu(di*(sum XW2n + self) + b2) — pure add, two half passes
    gather_half_k<false><<<25000, 256, 0, stream>>>(B1, cnt, colb, b2, B0);
    // XW3n = (h2 @ W3) * dinv[row]
    gemm_scaled_k<3><<<GEMM_BLKS, 512, 0, stream>>>(B0, W3, cnt, B1, 40);
    // logits + log-softmax
    gather40_lsm_k<<<NB_W, 256, 0, stream>>>(B1, cnt, colb, b3, out);
}